// Round 1
// baseline (1096.156 us; speedup 1.0000x reference)
//
#include <hip/hip_runtime.h>
#include <hip/hip_bf16.h>
#include <stdint.h>
#include <stddef.h>

// B=2, T=2048, D=2048, H=16, DH=128, F=8192, M=B*T=4096
using bf16_t = __hip_bfloat16;
typedef __attribute__((ext_vector_type(8))) short short8;
typedef __attribute__((ext_vector_type(4))) float f32x4;

__device__ __forceinline__ void gload_lds16(const void* g, void* l) {
  __builtin_amdgcn_global_load_lds((const __attribute__((address_space(1))) void*)g,
                                   (__attribute__((address_space(3))) void*)l,
                                   16, 0, 0);
}

// ---------- transpose + f32->bf16 convert: out[N][K] = in[K][N] ----------
__global__ __launch_bounds__(256) void k_transpose_cvt(const float* __restrict__ in,
                                                       bf16_t* __restrict__ out,
                                                       int K, int N) {
  __shared__ float tile[64][65];
  int n0 = blockIdx.x * 64, k0 = blockIdx.y * 64;
  int t = threadIdx.x;
#pragma unroll
  for (int i = 0; i < 16; ++i) {
    int idx = t + i * 256;
    int kk = idx >> 6, nn = idx & 63;
    tile[kk][nn] = in[(size_t)(k0 + kk) * N + n0 + nn];
  }
  __syncthreads();
#pragma unroll
  for (int i = 0; i < 16; ++i) {
    int idx = t + i * 256;
    int nn = idx >> 6, kk = idx & 63;
    out[(size_t)(n0 + nn) * K + k0 + kk] = __float2bfloat16(tile[kk][nn]);
  }
}

// ---------- layernorm f32 -> bf16, one block per row of 2048 ----------
__global__ __launch_bounds__(256) void k_layernorm(const float* __restrict__ x,
                                                   const float* __restrict__ gam,
                                                   const float* __restrict__ bet,
                                                   bf16_t* __restrict__ out) {
  int row = blockIdx.x, t = threadIdx.x;
  const float4* xr = (const float4*)(x + (size_t)row * 2048);
  float4 a = xr[t], b = xr[t + 256];
  float s  = a.x + a.y + a.z + a.w + b.x + b.y + b.z + b.w;
  float s2 = a.x*a.x + a.y*a.y + a.z*a.z + a.w*a.w
           + b.x*b.x + b.y*b.y + b.z*b.z + b.w*b.w;
#pragma unroll
  for (int off = 32; off >= 1; off >>= 1) {
    s  += __shfl_xor(s, off);
    s2 += __shfl_xor(s2, off);
  }
  __shared__ float red[8];
  if ((t & 63) == 0) { red[t >> 6] = s; red[4 + (t >> 6)] = s2; }
  __syncthreads();
  float S  = red[0] + red[1] + red[2] + red[3];
  float S2 = red[4] + red[5] + red[6] + red[7];
  float mu = S * (1.0f / 2048.0f);
  float var = S2 * (1.0f / 2048.0f) - mu * mu;
  float rstd = rsqrtf(var + 1e-6f);
  const float4* gv = (const float4*)gam;
  const float4* bv = (const float4*)bet;
  float4 g1 = gv[t], g2 = gv[t + 256], c1 = bv[t], c2 = bv[t + 256];
  bf16_t* orow = out + (size_t)row * 2048;
  orow[4*t + 0]    = __float2bfloat16((a.x - mu) * rstd * g1.x + c1.x);
  orow[4*t + 1]    = __float2bfloat16((a.y - mu) * rstd * g1.y + c1.y);
  orow[4*t + 2]    = __float2bfloat16((a.z - mu) * rstd * g1.z + c1.z);
  orow[4*t + 3]    = __float2bfloat16((a.w - mu) * rstd * g1.w + c1.w);
  orow[1024 + 4*t + 0] = __float2bfloat16((b.x - mu) * rstd * g2.x + c2.x);
  orow[1024 + 4*t + 1] = __float2bfloat16((b.y - mu) * rstd * g2.y + c2.y);
  orow[1024 + 4*t + 2] = __float2bfloat16((b.z - mu) * rstd * g2.z + c2.z);
  orow[1024 + 4*t + 3] = __float2bfloat16((b.w - mu) * rstd * g2.w + c2.w);
}

// ---------- GEMM: C[M,N] = A[M,K] (bf16, row-major) x Bt[N,K] (bf16) ----------
// EPI: 0 = bf16 out + bias ; 1 = bf16 out + bias + gelu(tanh) ; 2 = f32 out + bias + residual(inout Cf)
template <int EPI>
__global__ __launch_bounds__(256) void k_gemm(const bf16_t* __restrict__ A,
                                              const bf16_t* __restrict__ Bt,
                                              const float* __restrict__ bias,
                                              bf16_t* __restrict__ Cb,
                                              float* __restrict__ Cf,
                                              int Ndim, int Kdim) {
  __shared__ __align__(16) bf16_t As[128 * 32];
  __shared__ __align__(16) bf16_t Bs[128 * 32];
  int t = threadIdx.x;
  int m0 = blockIdx.y * 128, n0 = blockIdx.x * 128;
  int w = t >> 6, lane = t & 63;
  int wr = w >> 1, wc = w & 1;
  int lr = lane & 15, lk = lane >> 4;
  f32x4 acc[4][4] = {};
  const bf16_t* Arow = A + (size_t)m0 * Kdim;
  const bf16_t* Brow = Bt + (size_t)n0 * Kdim;
  for (int k0 = 0; k0 < Kdim; k0 += 32) {
#pragma unroll
    for (int i = 0; i < 2; ++i) {
      int idx = t + i * 256;
      int rr = idx >> 2, pp = idx & 3;
      gload_lds16(Arow + (size_t)rr * Kdim + k0 + pp * 8, (char*)As + idx * 16);
      gload_lds16(Brow + (size_t)rr * Kdim + k0 + pp * 8, (char*)Bs + idx * 16);
    }
    __syncthreads();
    short8 af[4], bfr[4];
#pragma unroll
    for (int mf = 0; mf < 4; ++mf)
      af[mf] = *(const short8*)(As + (wr * 64 + mf * 16 + lr) * 32 + lk * 8);
#pragma unroll
    for (int nf = 0; nf < 4; ++nf)
      bfr[nf] = *(const short8*)(Bs + (wc * 64 + nf * 16 + lr) * 32 + lk * 8);
#pragma unroll
    for (int mf = 0; mf < 4; ++mf)
#pragma unroll
      for (int nf = 0; nf < 4; ++nf)
        acc[mf][nf] = __builtin_amdgcn_mfma_f32_16x16x32_bf16(af[mf], bfr[nf], acc[mf][nf], 0, 0, 0);
    __syncthreads();
  }
#pragma unroll
  for (int mf = 0; mf < 4; ++mf) {
#pragma unroll
    for (int nf = 0; nf < 4; ++nf) {
#pragma unroll
      for (int r = 0; r < 4; ++r) {
        int rw = m0 + wr * 64 + mf * 16 + lk * 4 + r;
        int cl = n0 + wc * 64 + nf * 16 + lr;
        float v = acc[mf][nf][r] + bias[cl];
        size_t gi = (size_t)rw * Ndim + cl;
        if (EPI == 0) {
          Cb[gi] = __float2bfloat16(v);
        } else if (EPI == 1) {
          float u = v * (v * v * 0.044715f + 1.0f) * 0.7978845608028654f;
          float gl = 0.5f * v * (1.0f + tanhf(u));
          Cb[gi] = __float2bfloat16(gl);
        } else {
          Cf[gi] = v + Cf[gi];
        }
      }
    }
  }
}

// ---------- transpose V slice of qkv into vT[b][h][dh][t] ----------
__global__ __launch_bounds__(256) void k_transpose_v(const bf16_t* __restrict__ qkv,
                                                     bf16_t* __restrict__ vT) {
  __shared__ bf16_t tile[64][72];
  int bid = blockIdx.x;
  int tt = bid & 31;
  int dt = (bid >> 5) & 1;
  int h  = (bid >> 6) & 15;
  int b  = bid >> 10;
  int t0 = tt * 64, d0 = dt * 64;
  int t = threadIdx.x;
  const bf16_t* src = qkv + (size_t)(b * 2048) * 6144 + 4096 + h * 128;
#pragma unroll
  for (int i = 0; i < 16; ++i) {
    int idx = t + i * 256;
    int rr = idx >> 6, cc = idx & 63;          // rr: t-dim, cc: d-dim
    tile[rr][cc] = src[(size_t)(t0 + rr) * 6144 + d0 + cc];
  }
  __syncthreads();
  bf16_t* dst = vT + (size_t)(b * 16 + h) * 128 * 2048;
#pragma unroll
  for (int i = 0; i < 16; ++i) {
    int idx = t + i * 256;
    int rr = idx >> 6, cc = idx & 63;          // rr: d-dim, cc: t-dim
    dst[(size_t)(d0 + rr) * 2048 + t0 + cc] = tile[cc][rr];
  }
}

// ---------- causal flash attention + residual add: out = x + softmax(QK^T/sqrt(dh))V ----------
__global__ __launch_bounds__(256) void k_attn(const bf16_t* __restrict__ qkv,
                                              const bf16_t* __restrict__ vT,
                                              const float* __restrict__ x,
                                              float* __restrict__ out) {
  __shared__ __align__(16) bf16_t Pl[4][16][40];   // per-wave P bounce, stride 40 kills conflicts
  int bid = blockIdx.x;
  int qt = bid & 31;
  int h  = (bid >> 5) & 15;
  int b  = bid >> 9;
  int w = threadIdx.x >> 6, lane = threadIdx.x & 63;
  int lr = lane & 15, lk = lane >> 4;
  int q0 = qt * 64 + w * 16;                       // this wave's 16 q-rows
  const bf16_t* qb = qkv + (size_t)(b * 2048) * 6144 + h * 128;
  const bf16_t* kb = qb + 2048;
  const bf16_t* vb = vT + (size_t)(b * 16 + h) * 128 * 2048;
  short8 qf[4];
#pragma unroll
  for (int d4 = 0; d4 < 4; ++d4)
    qf[d4] = *(const short8*)(qb + (size_t)(q0 + lr) * 6144 + d4 * 32 + lk * 8);
  float m[4] = {-1e30f, -1e30f, -1e30f, -1e30f};
  float l[4] = {0.f, 0.f, 0.f, 0.f};
  f32x4 o[8] = {};
  int nkt = (q0 + 47) >> 5;
  const float sc = 0.08838834764831845f;           // 1/sqrt(128)
  for (int kt = 0; kt < nkt; ++kt) {
    int tk0 = kt * 32;
    f32x4 s[2] = {};
#pragma unroll
    for (int nt = 0; nt < 2; ++nt)
#pragma unroll
      for (int d4 = 0; d4 < 4; ++d4) {
        short8 kf = *(const short8*)(kb + (size_t)(tk0 + nt * 16 + lr) * 6144 + d4 * 32 + lk * 8);
        s[nt] = __builtin_amdgcn_mfma_f32_16x16x32_bf16(qf[d4], kf, s[nt], 0, 0, 0);
      }
    float sv[2][4], mt[4];
#pragma unroll
    for (int r = 0; r < 4; ++r) {
#pragma unroll
      for (int nt = 0; nt < 2; ++nt) {
        float v = s[nt][r] * sc;
        int kc = tk0 + nt * 16 + lr;
        int qr = q0 + lk * 4 + r;
        sv[nt][r] = (kc > qr) ? -1e30f : v;
      }
      mt[r] = fmaxf(sv[0][r], sv[1][r]);
    }
#pragma unroll
    for (int off = 1; off < 16; off <<= 1)
#pragma unroll
      for (int r = 0; r < 4; ++r) mt[r] = fmaxf(mt[r], __shfl_xor(mt[r], off));
    float alpha[4], rs[4];
#pragma unroll
    for (int r = 0; r < 4; ++r) {
      float mn = fmaxf(m[r], mt[r]);
      alpha[r] = __expf(m[r] - mn);
      m[r] = mn;
      rs[r] = 0.f;
    }
#pragma unroll
    for (int nt = 0; nt < 2; ++nt)
#pragma unroll
      for (int r = 0; r < 4; ++r) {
        float p = __expf(sv[nt][r] - m[r]);
        rs[r] += p;
        Pl[w][lk * 4 + r][nt * 16 + lr] = __float2bfloat16(p);
      }
#pragma unroll
    for (int off = 1; off < 16; off <<= 1)
#pragma unroll
      for (int r = 0; r < 4; ++r) rs[r] += __shfl_xor(rs[r], off);
#pragma unroll
    for (int r = 0; r < 4; ++r) l[r] = l[r] * alpha[r] + rs[r];
#pragma unroll
    for (int d8 = 0; d8 < 8; ++d8)
#pragma unroll
      for (int r = 0; r < 4; ++r) o[d8][r] *= alpha[r];
    asm volatile("s_waitcnt lgkmcnt(0)" ::: "memory");
    short8 pf = *(const short8*)(&Pl[w][lr][lk * 8]);
#pragma unroll
    for (int d8 = 0; d8 < 8; ++d8) {
      short8 vf = *(const short8*)(vb + (size_t)(d8 * 16 + lr) * 2048 + tk0 + lk * 8);
      o[d8] = __builtin_amdgcn_mfma_f32_16x16x32_bf16(pf, vf, o[d8], 0, 0, 0);
    }
  }
#pragma unroll
  for (int d8 = 0; d8 < 8; ++d8)
#pragma unroll
    for (int r = 0; r < 4; ++r) {
      int qr = q0 + lk * 4 + r;
      int cl = h * 128 + d8 * 16 + lr;
      size_t gi = (size_t)(b * 2048 + qr) * 2048 + cl;
      out[gi] = x[gi] + o[d8][r] / l[r];
    }
}

extern "C" void kernel_launch(void* const* d_in, const int* in_sizes, int n_in,
                              void* d_out, int out_size, void* d_ws, size_t ws_size,
                              hipStream_t stream) {
  const float* x    = (const float*)d_in[0];
  const float* ln1s = (const float*)d_in[1];
  const float* ln1b = (const float*)d_in[2];
  const float* wqkv = (const float*)d_in[3];
  const float* bqkv = (const float*)d_in[4];
  const float* ln2s = (const float*)d_in[5];
  const float* ln2b = (const float*)d_in[6];
  const float* w1   = (const float*)d_in[7];
  const float* b1   = (const float*)d_in[8];
  const float* w2   = (const float*)d_in[9];
  const float* b2   = (const float*)d_in[10];
  float* out = (float*)d_out;
  char* ws = (char*)d_ws;

  // ws layout (bytes); r/vT share one region (disjoint lifetimes), wqkvT aliases h.
  bf16_t* r     = (bf16_t*)(ws + 0);              // 16,777,216  [4096][2048]
  bf16_t* vT    = (bf16_t*)(ws + 0);              // same region [2][16][128][2048]
  bf16_t* qkv   = (bf16_t*)(ws + 16777216);       // 50,331,648  [4096][6144]
  bf16_t* w1T   = (bf16_t*)(ws + 67108864);       // 33,554,432  [8192][2048]
  bf16_t* w2T   = (bf16_t*)(ws + 100663296);      // 33,554,432  [2048][8192]
  bf16_t* h     = (bf16_t*)(ws + 134217728);      // 67,108,864  [4096][8192]
  bf16_t* wqkvT = (bf16_t*)(ws + 134217728);      // 25,165,824  [6144][2048] (dead before h is written)
  // total required: 201,326,592 bytes

  // weight transposes (f32 [K][N] -> bf16 [N][K])
  k_transpose_cvt<<<dim3(96, 32),  256, 0, stream>>>(wqkv, wqkvT, 2048, 6144);
  k_transpose_cvt<<<dim3(128, 32), 256, 0, stream>>>(w1,   w1T,   2048, 8192);
  k_transpose_cvt<<<dim3(32, 128), 256, 0, stream>>>(w2,   w2T,   8192, 2048);
  // LN1
  k_layernorm<<<4096, 256, 0, stream>>>(x, ln1s, ln1b, r);
  // QKV projection
  k_gemm<0><<<dim3(48, 32), 256, 0, stream>>>(r, wqkvT, bqkv, qkv, nullptr, 6144, 2048);
  // V transpose for PV operand
  k_transpose_v<<<2048, 256, 0, stream>>>(qkv, vT);
  // attention + residual (writes every element of d_out)
  k_attn<<<1024, 256, 0, stream>>>(qkv, vT, x, out);
  // LN2 on x2 = d_out
  k_layernorm<<<4096, 256, 0, stream>>>(out, ln2s, ln2b, r);
  // MLP
  k_gemm<1><<<dim3(64, 32), 256, 0, stream>>>(r, w1T, b1, h, nullptr, 8192, 2048);
  k_gemm<2><<<dim3(16, 32), 256, 0, stream>>>(h, w2T, b2, nullptr, out, 2048, 8192);
}

// Round 2
// 797.028 us; speedup vs baseline: 1.3753x; 1.3753x over previous
//
#include <hip/hip_runtime.h>
#include <hip/hip_bf16.h>
#include <stdint.h>
#include <stddef.h>

// B=2, T=2048, D=2048, H=16, DH=128, F=8192, M=B*T=4096
using bf16_t = __hip_bfloat16;
typedef __attribute__((ext_vector_type(8))) short short8;
typedef __attribute__((ext_vector_type(4))) float f32x4;

__device__ __forceinline__ void gload_lds16(const void* g, void* l) {
  __builtin_amdgcn_global_load_lds((const __attribute__((address_space(1))) void*)g,
                                   (__attribute__((address_space(3))) void*)l,
                                   16, 0, 0);
}

// ---------- transpose + f32->bf16 convert: out[N][K] = in[K][N] ----------
__global__ __launch_bounds__(256) void k_transpose_cvt(const float* __restrict__ in,
                                                       bf16_t* __restrict__ out,
                                                       int K, int N) {
  __shared__ float tile[64][65];
  int n0 = blockIdx.x * 64, k0 = blockIdx.y * 64;
  int t = threadIdx.x;
#pragma unroll
  for (int i = 0; i < 16; ++i) {
    int idx = t + i * 256;
    int kk = idx >> 6, nn = idx & 63;
    tile[kk][nn] = in[(size_t)(k0 + kk) * N + n0 + nn];
  }
  __syncthreads();
#pragma unroll
  for (int i = 0; i < 16; ++i) {
    int idx = t + i * 256;
    int nn = idx >> 6, kk = idx & 63;
    out[(size_t)(n0 + nn) * K + k0 + kk] = __float2bfloat16(tile[kk][nn]);
  }
}

// ---------- layernorm f32 -> bf16, one block per row of 2048 ----------
__global__ __launch_bounds__(256) void k_layernorm(const float* __restrict__ x,
                                                   const float* __restrict__ gam,
                                                   const float* __restrict__ bet,
                                                   bf16_t* __restrict__ out) {
  int row = blockIdx.x, t = threadIdx.x;
  const float4* xr = (const float4*)(x + (size_t)row * 2048);
  float4 a = xr[t], b = xr[t + 256];
  float s  = a.x + a.y + a.z + a.w + b.x + b.y + b.z + b.w;
  float s2 = a.x*a.x + a.y*a.y + a.z*a.z + a.w*a.w
           + b.x*b.x + b.y*b.y + b.z*b.z + b.w*b.w;
#pragma unroll
  for (int off = 32; off >= 1; off >>= 1) {
    s  += __shfl_xor(s, off);
    s2 += __shfl_xor(s2, off);
  }
  __shared__ float red[8];
  if ((t & 63) == 0) { red[t >> 6] = s; red[4 + (t >> 6)] = s2; }
  __syncthreads();
  float S  = red[0] + red[1] + red[2] + red[3];
  float S2 = red[4] + red[5] + red[6] + red[7];
  float mu = S * (1.0f / 2048.0f);
  float var = S2 * (1.0f / 2048.0f) - mu * mu;
  float rstd = rsqrtf(var + 1e-6f);
  const float4* gv = (const float4*)gam;
  const float4* bv = (const float4*)bet;
  float4 g1 = gv[t], g2 = gv[t + 256], c1 = bv[t], c2 = bv[t + 256];
  bf16_t* orow = out + (size_t)row * 2048;
  orow[4*t + 0]    = __float2bfloat16((a.x - mu) * rstd * g1.x + c1.x);
  orow[4*t + 1]    = __float2bfloat16((a.y - mu) * rstd * g1.y + c1.y);
  orow[4*t + 2]    = __float2bfloat16((a.z - mu) * rstd * g1.z + c1.z);
  orow[4*t + 3]    = __float2bfloat16((a.w - mu) * rstd * g1.w + c1.w);
  orow[1024 + 4*t + 0] = __float2bfloat16((b.x - mu) * rstd * g2.x + c2.x);
  orow[1024 + 4*t + 1] = __float2bfloat16((b.y - mu) * rstd * g2.y + c2.y);
  orow[1024 + 4*t + 2] = __float2bfloat16((b.z - mu) * rstd * g2.z + c2.z);
  orow[1024 + 4*t + 3] = __float2bfloat16((b.w - mu) * rstd * g2.w + c2.w);
}

// ---------- GEMM: C[M,N] = A[M,K] (bf16, row-major) x Bt[N,K] (bf16) ----------
// EPI: 0 = bf16 out + bias ; 1 = bf16 out + bias + gelu(tanh) ; 2 = f32 out + bias + residual(inout Cf)
template <int EPI>
__global__ __launch_bounds__(256) void k_gemm(const bf16_t* __restrict__ A,
                                              const bf16_t* __restrict__ Bt,
                                              const float* __restrict__ bias,
                                              bf16_t* __restrict__ Cb,
                                              float* __restrict__ Cf,
                                              int Ndim, int Kdim) {
  __shared__ __align__(16) bf16_t As[128 * 32];
  __shared__ __align__(16) bf16_t Bs[128 * 32];
  int t = threadIdx.x;
  int m0 = blockIdx.y * 128, n0 = blockIdx.x * 128;
  int w = t >> 6, lane = t & 63;
  int wr = w >> 1, wc = w & 1;
  int lr = lane & 15, lk = lane >> 4;
  f32x4 acc[4][4] = {};
  const bf16_t* Arow = A + (size_t)m0 * Kdim;
  const bf16_t* Brow = Bt + (size_t)n0 * Kdim;
  for (int k0 = 0; k0 < Kdim; k0 += 32) {
#pragma unroll
    for (int i = 0; i < 2; ++i) {
      int idx = t + i * 256;
      int rr = idx >> 2, pp = idx & 3;
      gload_lds16(Arow + (size_t)rr * Kdim + k0 + pp * 8, (char*)As + idx * 16);
      gload_lds16(Brow + (size_t)rr * Kdim + k0 + pp * 8, (char*)Bs + idx * 16);
    }
    __syncthreads();
    short8 af[4], bfr[4];
#pragma unroll
    for (int mf = 0; mf < 4; ++mf)
      af[mf] = *(const short8*)(As + (wr * 64 + mf * 16 + lr) * 32 + lk * 8);
#pragma unroll
    for (int nf = 0; nf < 4; ++nf)
      bfr[nf] = *(const short8*)(Bs + (wc * 64 + nf * 16 + lr) * 32 + lk * 8);
#pragma unroll
    for (int mf = 0; mf < 4; ++mf)
#pragma unroll
      for (int nf = 0; nf < 4; ++nf)
        acc[mf][nf] = __builtin_amdgcn_mfma_f32_16x16x32_bf16(af[mf], bfr[nf], acc[mf][nf], 0, 0, 0);
    __syncthreads();
  }
#pragma unroll
  for (int mf = 0; mf < 4; ++mf) {
#pragma unroll
    for (int nf = 0; nf < 4; ++nf) {
#pragma unroll
      for (int r = 0; r < 4; ++r) {
        int rw = m0 + wr * 64 + mf * 16 + lk * 4 + r;
        int cl = n0 + wc * 64 + nf * 16 + lr;
        float v = acc[mf][nf][r] + bias[cl];
        size_t gi = (size_t)rw * Ndim + cl;
        if (EPI == 0) {
          Cb[gi] = __float2bfloat16(v);
        } else if (EPI == 1) {
          float u = v * (v * v * 0.044715f + 1.0f) * 0.7978845608028654f;
          float gl = 0.5f * v * (1.0f + tanhf(u));
          Cb[gi] = __float2bfloat16(gl);
        } else {
          Cf[gi] = v + Cf[gi];
        }
      }
    }
  }
}

// ---------- transpose V slice of qkv into vT[b][h][dh][t] ----------
__global__ __launch_bounds__(256) void k_transpose_v(const bf16_t* __restrict__ qkv,
                                                     bf16_t* __restrict__ vT) {
  __shared__ bf16_t tile[64][72];
  int bid = blockIdx.x;
  int tt = bid & 31;
  int dt = (bid >> 5) & 1;
  int h  = (bid >> 6) & 15;
  int b  = bid >> 10;
  int t0 = tt * 64, d0 = dt * 64;
  int t = threadIdx.x;
  const bf16_t* src = qkv + (size_t)(b * 2048) * 6144 + 4096 + h * 128;
#pragma unroll
  for (int i = 0; i < 16; ++i) {
    int idx = t + i * 256;
    int rr = idx >> 6, cc = idx & 63;          // rr: t-dim, cc: d-dim
    tile[rr][cc] = src[(size_t)(t0 + rr) * 6144 + d0 + cc];
  }
  __syncthreads();
  bf16_t* dst = vT + (size_t)(b * 16 + h) * 128 * 2048;
#pragma unroll
  for (int i = 0; i < 16; ++i) {
    int idx = t + i * 256;
    int rr = idx >> 6, cc = idx & 63;          // rr: d-dim, cc: t-dim
    dst[(size_t)(d0 + rr) * 2048 + t0 + cc] = tile[cc][rr];
  }
}

// ---------- causal flash attention + residual add: out = x + softmax(QK^T/sqrt(dh))V ----------
// One wave owns 32 q-rows (2x16 fragments). KBLK=32. 512 blocks x 4 waves.
// Block j: bh = j&31, cq = j>>5; waves get q-chunks {cq, 63-cq, 31-cq, 32+cq}
// so every block has exactly 130 iterations of total work (balanced).
__global__ __launch_bounds__(256, 2) void k_attn(const bf16_t* __restrict__ qkv,
                                                 const bf16_t* __restrict__ vT,
                                                 const float* __restrict__ x,
                                                 float* __restrict__ out) {
  __shared__ __align__(16) bf16_t Pl[4][32][40];   // per-wave P bounce, stride 40
  int j = blockIdx.x;
  int bh = j & 31;
  int cq = j >> 5;                                  // 0..15
  int b = bh >> 4, h = bh & 15;
  int w = threadIdx.x >> 6, lane = threadIdx.x & 63;
  int lr = lane & 15, lk = lane >> 4;
  int c = (w == 0) ? cq : (w == 1) ? (63 - cq) : (w == 2) ? (31 - cq) : (32 + cq);
  int q0 = c * 32;                                  // this wave's 32 q-rows
  const bf16_t* qb = qkv + (size_t)(b * 2048) * 6144 + h * 128;
  const bf16_t* kb = qb + 2048;
  const bf16_t* vb = vT + (size_t)(b * 16 + h) * 128 * 2048;
  short8 qf[2][4];
#pragma unroll
  for (int qg = 0; qg < 2; ++qg)
#pragma unroll
    for (int d4 = 0; d4 < 4; ++d4)
      qf[qg][d4] = *(const short8*)(qb + (size_t)(q0 + qg * 16 + lr) * 6144 + d4 * 32 + lk * 8);
  float m[2][4], l[2][4];
#pragma unroll
  for (int qg = 0; qg < 2; ++qg)
#pragma unroll
    for (int r = 0; r < 4; ++r) { m[qg][r] = -1e30f; l[qg][r] = 0.f; }
  f32x4 o[2][8] = {};
  int nkt = c + 1;
  const float sc = 0.08838834764831845f;           // 1/sqrt(128)
  for (int kt = 0; kt < nkt; ++kt) {
    int tk0 = kt * 32;
    // --- issue ALL loads for this iteration up front (16 outstanding) ---
    short8 vf[8];
#pragma unroll
    for (int d8 = 0; d8 < 8; ++d8)
      vf[d8] = *(const short8*)(vb + (size_t)(d8 * 16 + lr) * 2048 + tk0 + lk * 8);
    short8 kf[2][4];
#pragma unroll
    for (int nt = 0; nt < 2; ++nt)
#pragma unroll
      for (int d4 = 0; d4 < 4; ++d4)
        kf[nt][d4] = *(const short8*)(kb + (size_t)(tk0 + nt * 16 + lr) * 6144 + d4 * 32 + lk * 8);
    // --- QK^T: 16 MFMAs, 4 independent accumulator chains ---
    f32x4 s[2][2] = {};
#pragma unroll
    for (int d4 = 0; d4 < 4; ++d4)
#pragma unroll
      for (int qg = 0; qg < 2; ++qg)
#pragma unroll
        for (int nt = 0; nt < 2; ++nt)
          s[qg][nt] = __builtin_amdgcn_mfma_f32_16x16x32_bf16(qf[qg][d4], kf[nt][d4], s[qg][nt], 0, 0, 0);
    // --- online softmax (per 16-row group, independent chains) ---
#pragma unroll
    for (int qg = 0; qg < 2; ++qg) {
      float sv[2][4], mt[4];
#pragma unroll
      for (int r = 0; r < 4; ++r) {
        int qr = q0 + qg * 16 + lk * 4 + r;
#pragma unroll
        for (int nt = 0; nt < 2; ++nt) {
          float v = s[qg][nt][r] * sc;
          int kc = tk0 + nt * 16 + lr;
          sv[nt][r] = (kc > qr) ? -1e30f : v;
        }
        mt[r] = fmaxf(sv[0][r], sv[1][r]);
      }
#pragma unroll
      for (int off = 1; off < 16; off <<= 1)
#pragma unroll
        for (int r = 0; r < 4; ++r) mt[r] = fmaxf(mt[r], __shfl_xor(mt[r], off));
      float alpha[4], rs[4];
#pragma unroll
      for (int r = 0; r < 4; ++r) {
        float mn = fmaxf(m[qg][r], mt[r]);
        alpha[r] = __expf(m[qg][r] - mn);
        m[qg][r] = mn;
      }
#pragma unroll
      for (int r = 0; r < 4; ++r) {
        float p0 = __expf(sv[0][r] - m[qg][r]);
        float p1 = __expf(sv[1][r] - m[qg][r]);
        rs[r] = p0 + p1;
        Pl[w][qg * 16 + lk * 4 + r][lr]      = __float2bfloat16(p0);
        Pl[w][qg * 16 + lk * 4 + r][16 + lr] = __float2bfloat16(p1);
      }
#pragma unroll
      for (int off = 1; off < 16; off <<= 1)
#pragma unroll
        for (int r = 0; r < 4; ++r) rs[r] += __shfl_xor(rs[r], off);
#pragma unroll
      for (int r = 0; r < 4; ++r) l[qg][r] = l[qg][r] * alpha[r] + rs[r];
#pragma unroll
      for (int d8 = 0; d8 < 8; ++d8)
#pragma unroll
        for (int r = 0; r < 4; ++r) o[qg][d8][r] *= alpha[r];
    }
    asm volatile("s_waitcnt lgkmcnt(0)" ::: "memory");
    short8 pf[2];
#pragma unroll
    for (int qg = 0; qg < 2; ++qg)
      pf[qg] = *(const short8*)(&Pl[w][qg * 16 + lr][lk * 8]);
    // --- PV: 16 MFMAs, V already in registers ---
#pragma unroll
    for (int d8 = 0; d8 < 8; ++d8)
#pragma unroll
      for (int qg = 0; qg < 2; ++qg)
        o[qg][d8] = __builtin_amdgcn_mfma_f32_16x16x32_bf16(pf[qg], vf[d8], o[qg][d8], 0, 0, 0);
  }
#pragma unroll
  for (int qg = 0; qg < 2; ++qg)
#pragma unroll
    for (int d8 = 0; d8 < 8; ++d8)
#pragma unroll
      for (int r = 0; r < 4; ++r) {
        int qr = q0 + qg * 16 + lk * 4 + r;
        int cl = h * 128 + d8 * 16 + lr;
        size_t gi = (size_t)(b * 2048 + qr) * 2048 + cl;
        out[gi] = x[gi] + o[qg][d8][r] / l[qg][r];
      }
}

extern "C" void kernel_launch(void* const* d_in, const int* in_sizes, int n_in,
                              void* d_out, int out_size, void* d_ws, size_t ws_size,
                              hipStream_t stream) {
  const float* x    = (const float*)d_in[0];
  const float* ln1s = (const float*)d_in[1];
  const float* ln1b = (const float*)d_in[2];
  const float* wqkv = (const float*)d_in[3];
  const float* bqkv = (const float*)d_in[4];
  const float* ln2s = (const float*)d_in[5];
  const float* ln2b = (const float*)d_in[6];
  const float* w1   = (const float*)d_in[7];
  const float* b1   = (const float*)d_in[8];
  const float* w2   = (const float*)d_in[9];
  const float* b2   = (const float*)d_in[10];
  float* out = (float*)d_out;
  char* ws = (char*)d_ws;

  // ws layout (bytes); r/vT share one region (disjoint lifetimes), wqkvT aliases h.
  bf16_t* r     = (bf16_t*)(ws + 0);              // 16,777,216  [4096][2048]
  bf16_t* vT    = (bf16_t*)(ws + 0);              // same region [2][16][128][2048]
  bf16_t* qkv   = (bf16_t*)(ws + 16777216);       // 50,331,648  [4096][6144]
  bf16_t* w1T   = (bf16_t*)(ws + 67108864);       // 33,554,432  [8192][2048]
  bf16_t* w2T   = (bf16_t*)(ws + 100663296);      // 33,554,432  [2048][8192]
  bf16_t* h     = (bf16_t*)(ws + 134217728);      // 67,108,864  [4096][8192]
  bf16_t* wqkvT = (bf16_t*)(ws + 134217728);      // 25,165,824  [6144][2048] (dead before h is written)
  // total required: 201,326,592 bytes

  // weight transposes (f32 [K][N] -> bf16 [N][K])
  k_transpose_cvt<<<dim3(96, 32),  256, 0, stream>>>(wqkv, wqkvT, 2048, 6144);
  k_transpose_cvt<<<dim3(128, 32), 256, 0, stream>>>(w1,   w1T,   2048, 8192);
  k_transpose_cvt<<<dim3(32, 128), 256, 0, stream>>>(w2,   w2T,   8192, 2048);
  // LN1
  k_layernorm<<<4096, 256, 0, stream>>>(x, ln1s, ln1b, r);
  // QKV projection
  k_gemm<0><<<dim3(48, 32), 256, 0, stream>>>(r, wqkvT, bqkv, qkv, nullptr, 6144, 2048);
  // V transpose for PV operand
  k_transpose_v<<<2048, 256, 0, stream>>>(qkv, vT);
  // attention + residual (writes every element of d_out)
  k_attn<<<512, 256, 0, stream>>>(qkv, vT, x, out);
  // LN2 on x2 = d_out
  k_layernorm<<<4096, 256, 0, stream>>>(out, ln2s, ln2b, r);
  // MLP
  k_gemm<1><<<dim3(64, 32), 256, 0, stream>>>(r, w1T, b1, h, nullptr, 8192, 2048);
  k_gemm<2><<<dim3(16, 32), 256, 0, stream>>>(h, w2T, b2, nullptr, out, 2048, 8192);
}

// Round 3
// 751.748 us; speedup vs baseline: 1.4581x; 1.0602x over previous
//
#include <hip/hip_runtime.h>
#include <hip/hip_bf16.h>
#include <stdint.h>
#include <stddef.h>

// B=2, T=2048, D=2048, H=16, DH=128, F=8192, M=B*T=4096
using bf16_t = __hip_bfloat16;
typedef __attribute__((ext_vector_type(8))) short short8;
typedef __attribute__((ext_vector_type(4))) float f32x4;

__device__ __forceinline__ void gload_lds16(const void* g, void* l) {
  __builtin_amdgcn_global_load_lds((const __attribute__((address_space(1))) void*)g,
                                   (__attribute__((address_space(3))) void*)l,
                                   16, 0, 0);
}

// ---------- transpose + f32->bf16 convert: out[N][K] = in[K][N] ----------
__global__ __launch_bounds__(256) void k_transpose_cvt(const float* __restrict__ in,
                                                       bf16_t* __restrict__ out,
                                                       int K, int N) {
  __shared__ float tile[64][65];
  int n0 = blockIdx.x * 64, k0 = blockIdx.y * 64;
  int t = threadIdx.x;
#pragma unroll
  for (int i = 0; i < 16; ++i) {
    int idx = t + i * 256;
    int kk = idx >> 6, nn = idx & 63;
    tile[kk][nn] = in[(size_t)(k0 + kk) * N + n0 + nn];
  }
  __syncthreads();
#pragma unroll
  for (int i = 0; i < 16; ++i) {
    int idx = t + i * 256;
    int nn = idx >> 6, kk = idx & 63;
    out[(size_t)(n0 + nn) * K + k0 + kk] = __float2bfloat16(tile[kk][nn]);
  }
}

// ---------- layernorm f32 -> bf16, one block per row of 2048 ----------
__global__ __launch_bounds__(256) void k_layernorm(const float* __restrict__ x,
                                                   const float* __restrict__ gam,
                                                   const float* __restrict__ bet,
                                                   bf16_t* __restrict__ out) {
  int row = blockIdx.x, t = threadIdx.x;
  const float4* xr = (const float4*)(x + (size_t)row * 2048);
  float4 a = xr[t], b = xr[t + 256];
  float s  = a.x + a.y + a.z + a.w + b.x + b.y + b.z + b.w;
  float s2 = a.x*a.x + a.y*a.y + a.z*a.z + a.w*a.w
           + b.x*b.x + b.y*b.y + b.z*b.z + b.w*b.w;
#pragma unroll
  for (int off = 32; off >= 1; off >>= 1) {
    s  += __shfl_xor(s, off);
    s2 += __shfl_xor(s2, off);
  }
  __shared__ float red[8];
  if ((t & 63) == 0) { red[t >> 6] = s; red[4 + (t >> 6)] = s2; }
  __syncthreads();
  float S  = red[0] + red[1] + red[2] + red[3];
  float S2 = red[4] + red[5] + red[6] + red[7];
  float mu = S * (1.0f / 2048.0f);
  float var = S2 * (1.0f / 2048.0f) - mu * mu;
  float rstd = rsqrtf(var + 1e-6f);
  const float4* gv = (const float4*)gam;
  const float4* bv = (const float4*)bet;
  float4 g1 = gv[t], g2 = gv[t + 256], c1 = bv[t], c2 = bv[t + 256];
  bf16_t* orow = out + (size_t)row * 2048;
  orow[4*t + 0]    = __float2bfloat16((a.x - mu) * rstd * g1.x + c1.x);
  orow[4*t + 1]    = __float2bfloat16((a.y - mu) * rstd * g1.y + c1.y);
  orow[4*t + 2]    = __float2bfloat16((a.z - mu) * rstd * g1.z + c1.z);
  orow[4*t + 3]    = __float2bfloat16((a.w - mu) * rstd * g1.w + c1.w);
  orow[1024 + 4*t + 0] = __float2bfloat16((b.x - mu) * rstd * g2.x + c2.x);
  orow[1024 + 4*t + 1] = __float2bfloat16((b.y - mu) * rstd * g2.y + c2.y);
  orow[1024 + 4*t + 2] = __float2bfloat16((b.z - mu) * rstd * g2.z + c2.z);
  orow[1024 + 4*t + 3] = __float2bfloat16((b.w - mu) * rstd * g2.w + c2.w);
}

// ---------- 8-phase 256-row GEMM: C[M,N] = A[M,K] x Bt[N,K] (both bf16) ----------
// BM=256, BK=64, BN_ in {128,256}. 512 threads = 8 waves (2 M x 4 N).
// Per-wave C = 128 x (BN_/4). 4 quadrant-phases per K-tile, double-buffered LDS,
// XOR-16B swizzle applied to global_load_lds SOURCE and ds_read address (both sides).
// EPI: 0 = bf16 out + bias ; 1 = bf16 + bias + gelu ; 2 = f32 + bias + residual.
template <int EPI, int BN_>
__global__ __launch_bounds__(512, 2) void k_gemm2(const bf16_t* __restrict__ A,
                                                  const bf16_t* __restrict__ Bt,
                                                  const float* __restrict__ bias,
                                                  bf16_t* __restrict__ Cb,
                                                  float* __restrict__ Cf,
                                                  int Ndim, int Kdim) {
  constexpr int WN = BN_ / 4;                 // per-wave N width: 64 or 32
  constexpr int NF = WN / 16;                 // n-frags per wave: 4 or 2
  constexpr int NQ = NF / 2;                  // n-frags per quadrant: 2 or 1
  constexpr int BLOADS = (BN_ * 64 * 2) / (512 * 16);  // 4 or 2 loads/thread
  __shared__ __align__(16) bf16_t Abuf[2][256 * 64];
  __shared__ __align__(16) bf16_t Bbuf[2][BN_ * 64];
  // bijective XCD swizzle (all grids are multiples of 8); GM = 16 (M = 4096)
  int nwg = gridDim.x;
  int orig = blockIdx.x;
  int wg = (orig & 7) * (nwg >> 3) + (orig >> 3);
  int m0 = (wg & 15) * 256;
  int n0 = (wg >> 4) * BN_;
  int tid = threadIdx.x;
  int w = tid >> 6, lane = tid & 63;
  int lr = lane & 15, lk = lane >> 4;
  int wr = w >> 2, wc = w & 3;
  const int NT = Kdim >> 6;
  const bf16_t* Ag = A + (size_t)m0 * Kdim;
  const bf16_t* Bg = Bt + (size_t)n0 * Kdim;

  f32x4 acc[8][NF];
#pragma unroll
  for (int i = 0; i < 8; ++i)
#pragma unroll
    for (int j = 0; j < NF; ++j) acc[i][j] = (f32x4){0.f, 0.f, 0.f, 0.f};

  // prologue: stage tile 0 into buffer 0 (source pre-swizzled, LDS linear)
#pragma unroll
  for (int li = 0; li < 4; ++li) {
    int o = li * 512 + tid;
    int row = o >> 3, c16 = o & 7;
    gload_lds16(Ag + (size_t)row * Kdim + ((c16 ^ (row & 7)) << 3), &Abuf[0][o * 8]);
  }
#pragma unroll
  for (int li = 0; li < BLOADS; ++li) {
    int o = li * 512 + tid;
    int row = o >> 3, c16 = o & 7;
    gload_lds16(Bg + (size_t)row * Kdim + ((c16 ^ (row & 7)) << 3), &Bbuf[0][o * 8]);
  }
  asm volatile("s_waitcnt vmcnt(0)" ::: "memory");
  asm volatile("s_barrier" ::: "memory");

  short8 af[4][2], bq[NQ][2];
  for (int t = 0; t < NT; ++t) {
    int p = t & 1;
    const bf16_t* An = Ag + (size_t)(t + 1) * 64;
    const bf16_t* Bn = Bg + (size_t)(t + 1) * 64;
    bool pre = (t + 1 < NT);
    // ---- phase 0: quadrant (m-lo, n-lo); stage A of tile t+1 ----
#pragma unroll
    for (int mf = 0; mf < 4; ++mf)
#pragma unroll
      for (int ks = 0; ks < 2; ++ks) {
        int row = wr * 128 + mf * 16 + lr;
        int c16 = (ks * 4 + lk) ^ (lr & 7);
        af[mf][ks] = *(const short8*)&Abuf[p][row * 64 + c16 * 8];
      }
#pragma unroll
    for (int nf = 0; nf < NQ; ++nf)
#pragma unroll
      for (int ks = 0; ks < 2; ++ks) {
        int row = wc * WN + nf * 16 + lr;
        int c16 = (ks * 4 + lk) ^ (lr & 7);
        bq[nf][ks] = *(const short8*)&Bbuf[p][row * 64 + c16 * 8];
      }
    if (pre) {
#pragma unroll
      for (int li = 0; li < 4; ++li) {
        int o = li * 512 + tid;
        int row = o >> 3, c16 = o & 7;
        gload_lds16(An + (size_t)row * Kdim + ((c16 ^ (row & 7)) << 3), &Abuf[p ^ 1][o * 8]);
      }
    }
    asm volatile("s_barrier" ::: "memory");
    asm volatile("s_waitcnt lgkmcnt(0)" ::: "memory");
    __builtin_amdgcn_sched_barrier(0);
    __builtin_amdgcn_s_setprio(1);
#pragma unroll
    for (int ks = 0; ks < 2; ++ks)
#pragma unroll
      for (int mf = 0; mf < 4; ++mf)
#pragma unroll
        for (int nf = 0; nf < NQ; ++nf)
          acc[mf][nf] = __builtin_amdgcn_mfma_f32_16x16x32_bf16(af[mf][ks], bq[nf][ks], acc[mf][nf], 0, 0, 0);
    __builtin_amdgcn_s_setprio(0);
    asm volatile("s_barrier" ::: "memory");
    // ---- phase 1: quadrant (m-lo, n-hi); stage B of tile t+1 ----
#pragma unroll
    for (int nf = 0; nf < NQ; ++nf)
#pragma unroll
      for (int ks = 0; ks < 2; ++ks) {
        int row = wc * WN + (NQ + nf) * 16 + lr;
        int c16 = (ks * 4 + lk) ^ (lr & 7);
        bq[nf][ks] = *(const short8*)&Bbuf[p][row * 64 + c16 * 8];
      }
    if (pre) {
#pragma unroll
      for (int li = 0; li < BLOADS; ++li) {
        int o = li * 512 + tid;
        int row = o >> 3, c16 = o & 7;
        gload_lds16(Bn + (size_t)row * Kdim + ((c16 ^ (row & 7)) << 3), &Bbuf[p ^ 1][o * 8]);
      }
    }
    asm volatile("s_barrier" ::: "memory");
    asm volatile("s_waitcnt lgkmcnt(0)" ::: "memory");
    __builtin_amdgcn_sched_barrier(0);
    __builtin_amdgcn_s_setprio(1);
#pragma unroll
    for (int ks = 0; ks < 2; ++ks)
#pragma unroll
      for (int mf = 0; mf < 4; ++mf)
#pragma unroll
        for (int nf = 0; nf < NQ; ++nf)
          acc[mf][NQ + nf] = __builtin_amdgcn_mfma_f32_16x16x32_bf16(af[mf][ks], bq[nf][ks], acc[mf][NQ + nf], 0, 0, 0);
    __builtin_amdgcn_s_setprio(0);
    asm volatile("s_barrier" ::: "memory");
    // ---- phase 2: quadrant (m-hi, n-hi) ----
#pragma unroll
    for (int mf = 0; mf < 4; ++mf)
#pragma unroll
      for (int ks = 0; ks < 2; ++ks) {
        int row = wr * 128 + (4 + mf) * 16 + lr;
        int c16 = (ks * 4 + lk) ^ (lr & 7);
        af[mf][ks] = *(const short8*)&Abuf[p][row * 64 + c16 * 8];
      }
    asm volatile("s_barrier" ::: "memory");
    asm volatile("s_waitcnt lgkmcnt(0)" ::: "memory");
    __builtin_amdgcn_sched_barrier(0);
    __builtin_amdgcn_s_setprio(1);
#pragma unroll
    for (int ks = 0; ks < 2; ++ks)
#pragma unroll
      for (int mf = 0; mf < 4; ++mf)
#pragma unroll
        for (int nf = 0; nf < NQ; ++nf)
          acc[4 + mf][NQ + nf] = __builtin_amdgcn_mfma_f32_16x16x32_bf16(af[mf][ks], bq[nf][ks], acc[4 + mf][NQ + nf], 0, 0, 0);
    __builtin_amdgcn_s_setprio(0);
    asm volatile("s_barrier" ::: "memory");
    // ---- phase 3: quadrant (m-hi, n-lo); vmcnt(0) after MFMA (loads 2-3 phases old) ----
#pragma unroll
    for (int nf = 0; nf < NQ; ++nf)
#pragma unroll
      for (int ks = 0; ks < 2; ++ks) {
        int row = wc * WN + nf * 16 + lr;
        int c16 = (ks * 4 + lk) ^ (lr & 7);
        bq[nf][ks] = *(const short8*)&Bbuf[p][row * 64 + c16 * 8];
      }
    asm volatile("s_barrier" ::: "memory");
    asm volatile("s_waitcnt lgkmcnt(0)" ::: "memory");
    __builtin_amdgcn_sched_barrier(0);
    __builtin_amdgcn_s_setprio(1);
#pragma unroll
    for (int ks = 0; ks < 2; ++ks)
#pragma unroll
      for (int mf = 0; mf < 4; ++mf)
#pragma unroll
        for (int nf = 0; nf < NQ; ++nf)
          acc[4 + mf][nf] = __builtin_amdgcn_mfma_f32_16x16x32_bf16(af[mf][ks], bq[nf][ks], acc[4 + mf][nf], 0, 0, 0);
    __builtin_amdgcn_s_setprio(0);
    asm volatile("s_waitcnt vmcnt(0)" ::: "memory");
    asm volatile("s_barrier" ::: "memory");
  }
  // ---- epilogue ----
#pragma unroll
  for (int mf = 0; mf < 8; ++mf) {
#pragma unroll
    for (int nf = 0; nf < NF; ++nf) {
#pragma unroll
      for (int r = 0; r < 4; ++r) {
        int rw = m0 + wr * 128 + mf * 16 + lk * 4 + r;
        int cl = n0 + wc * WN + nf * 16 + lr;
        float v = acc[mf][nf][r] + bias[cl];
        size_t gi = (size_t)rw * Ndim + cl;
        if (EPI == 0) {
          Cb[gi] = __float2bfloat16(v);
        } else if (EPI == 1) {
          float u = v * (v * v * 0.044715f + 1.0f) * 0.7978845608028654f;
          float gl = 0.5f * v * (1.0f + tanhf(u));
          Cb[gi] = __float2bfloat16(gl);
        } else {
          Cf[gi] = v + Cf[gi];
        }
      }
    }
  }
}

// ---------- transpose V slice of qkv into vT[b][h][dh][t] ----------
__global__ __launch_bounds__(256) void k_transpose_v(const bf16_t* __restrict__ qkv,
                                                     bf16_t* __restrict__ vT) {
  __shared__ bf16_t tile[64][72];
  int bid = blockIdx.x;
  int tt = bid & 31;
  int dt = (bid >> 5) & 1;
  int h  = (bid >> 6) & 15;
  int b  = bid >> 10;
  int t0 = tt * 64, d0 = dt * 64;
  int t = threadIdx.x;
  const bf16_t* src = qkv + (size_t)(b * 2048) * 6144 + 4096 + h * 128;
#pragma unroll
  for (int i = 0; i < 16; ++i) {
    int idx = t + i * 256;
    int rr = idx >> 6, cc = idx & 63;          // rr: t-dim, cc: d-dim
    tile[rr][cc] = src[(size_t)(t0 + rr) * 6144 + d0 + cc];
  }
  __syncthreads();
  bf16_t* dst = vT + (size_t)(b * 16 + h) * 128 * 2048;
#pragma unroll
  for (int i = 0; i < 16; ++i) {
    int idx = t + i * 256;
    int rr = idx >> 6, cc = idx & 63;          // rr: d-dim, cc: t-dim
    dst[(size_t)(d0 + rr) * 2048 + t0 + cc] = tile[cc][rr];
  }
}

// ---------- causal flash attention + residual add: out = x + softmax(QK^T/sqrt(dh))V ----------
// One wave owns 32 q-rows (2x16 fragments). KBLK=32. 512 blocks x 4 waves.
// Block j: bh = j&31, cq = j>>5; waves get q-chunks {cq, 63-cq, 31-cq, 32+cq}
// so every block has exactly 130 iterations of total work (balanced).
__global__ __launch_bounds__(256, 2) void k_attn(const bf16_t* __restrict__ qkv,
                                                 const bf16_t* __restrict__ vT,
                                                 const float* __restrict__ x,
                                                 float* __restrict__ out) {
  __shared__ __align__(16) bf16_t Pl[4][32][40];   // per-wave P bounce, stride 40
  int j = blockIdx.x;
  int bh = j & 31;
  int cq = j >> 5;                                  // 0..15
  int b = bh >> 4, h = bh & 15;
  int w = threadIdx.x >> 6, lane = threadIdx.x & 63;
  int lr = lane & 15, lk = lane >> 4;
  int c = (w == 0) ? cq : (w == 1) ? (63 - cq) : (w == 2) ? (31 - cq) : (32 + cq);
  int q0 = c * 32;                                  // this wave's 32 q-rows
  const bf16_t* qb = qkv + (size_t)(b * 2048) * 6144 + h * 128;
  const bf16_t* kb = qb + 2048;
  const bf16_t* vb = vT + (size_t)(b * 16 + h) * 128 * 2048;
  short8 qf[2][4];
#pragma unroll
  for (int qg = 0; qg < 2; ++qg)
#pragma unroll
    for (int d4 = 0; d4 < 4; ++d4)
      qf[qg][d4] = *(const short8*)(qb + (size_t)(q0 + qg * 16 + lr) * 6144 + d4 * 32 + lk * 8);
  float m[2][4], l[2][4];
#pragma unroll
  for (int qg = 0; qg < 2; ++qg)
#pragma unroll
    for (int r = 0; r < 4; ++r) { m[qg][r] = -1e30f; l[qg][r] = 0.f; }
  f32x4 o[2][8] = {};
  int nkt = c + 1;
  const float sc = 0.08838834764831845f;           // 1/sqrt(128)
  for (int kt = 0; kt < nkt; ++kt) {
    int tk0 = kt * 32;
    short8 vf[8];
#pragma unroll
    for (int d8 = 0; d8 < 8; ++d8)
      vf[d8] = *(const short8*)(vb + (size_t)(d8 * 16 + lr) * 2048 + tk0 + lk * 8);
    short8 kf[2][4];
#pragma unroll
    for (int nt = 0; nt < 2; ++nt)
#pragma unroll
      for (int d4 = 0; d4 < 4; ++d4)
        kf[nt][d4] = *(const short8*)(kb + (size_t)(tk0 + nt * 16 + lr) * 6144 + d4 * 32 + lk * 8);
    f32x4 s[2][2] = {};
#pragma unroll
    for (int d4 = 0; d4 < 4; ++d4)
#pragma unroll
      for (int qg = 0; qg < 2; ++qg)
#pragma unroll
        for (int nt = 0; nt < 2; ++nt)
          s[qg][nt] = __builtin_amdgcn_mfma_f32_16x16x32_bf16(qf[qg][d4], kf[nt][d4], s[qg][nt], 0, 0, 0);
#pragma unroll
    for (int qg = 0; qg < 2; ++qg) {
      float sv[2][4], mt[4];
#pragma unroll
      for (int r = 0; r < 4; ++r) {
        int qr = q0 + qg * 16 + lk * 4 + r;
#pragma unroll
        for (int nt = 0; nt < 2; ++nt) {
          float v = s[qg][nt][r] * sc;
          int kc = tk0 + nt * 16 + lr;
          sv[nt][r] = (kc > qr) ? -1e30f : v;
        }
        mt[r] = fmaxf(sv[0][r], sv[1][r]);
      }
#pragma unroll
      for (int off = 1; off < 16; off <<= 1)
#pragma unroll
        for (int r = 0; r < 4; ++r) mt[r] = fmaxf(mt[r], __shfl_xor(mt[r], off));
      float alpha[4], rs[4];
#pragma unroll
      for (int r = 0; r < 4; ++r) {
        float mn = fmaxf(m[qg][r], mt[r]);
        alpha[r] = __expf(m[qg][r] - mn);
        m[qg][r] = mn;
      }
#pragma unroll
      for (int r = 0; r < 4; ++r) {
        float p0 = __expf(sv[0][r] - m[qg][r]);
        float p1 = __expf(sv[1][r] - m[qg][r]);
        rs[r] = p0 + p1;
        Pl[w][qg * 16 + lk * 4 + r][lr]      = __float2bfloat16(p0);
        Pl[w][qg * 16 + lk * 4 + r][16 + lr] = __float2bfloat16(p1);
      }
#pragma unroll
      for (int off = 1; off < 16; off <<= 1)
#pragma unroll
        for (int r = 0; r < 4; ++r) rs[r] += __shfl_xor(rs[r], off);
#pragma unroll
      for (int r = 0; r < 4; ++r) l[qg][r] = l[qg][r] * alpha[r] + rs[r];
#pragma unroll
      for (int d8 = 0; d8 < 8; ++d8)
#pragma unroll
        for (int r = 0; r < 4; ++r) o[qg][d8][r] *= alpha[r];
    }
    asm volatile("s_waitcnt lgkmcnt(0)" ::: "memory");
    short8 pf[2];
#pragma unroll
    for (int qg = 0; qg < 2; ++qg)
      pf[qg] = *(const short8*)(&Pl[w][qg * 16 + lr][lk * 8]);
#pragma unroll
    for (int d8 = 0; d8 < 8; ++d8)
#pragma unroll
      for (int qg = 0; qg < 2; ++qg)
        o[qg][d8] = __builtin_amdgcn_mfma_f32_16x16x32_bf16(pf[qg], vf[d8], o[qg][d8], 0, 0, 0);
  }
#pragma unroll
  for (int qg = 0; qg < 2; ++qg)
#pragma unroll
    for (int d8 = 0; d8 < 8; ++d8)
#pragma unroll
      for (int r = 0; r < 4; ++r) {
        int qr = q0 + qg * 16 + lk * 4 + r;
        int cl = h * 128 + d8 * 16 + lr;
        size_t gi = (size_t)(b * 2048 + qr) * 2048 + cl;
        out[gi] = x[gi] + o[qg][d8][r] / l[qg][r];
      }
}

extern "C" void kernel_launch(void* const* d_in, const int* in_sizes, int n_in,
                              void* d_out, int out_size, void* d_ws, size_t ws_size,
                              hipStream_t stream) {
  const float* x    = (const float*)d_in[0];
  const float* ln1s = (const float*)d_in[1];
  const float* ln1b = (const float*)d_in[2];
  const float* wqkv = (const float*)d_in[3];
  const float* bqkv = (const float*)d_in[4];
  const float* ln2s = (const float*)d_in[5];
  const float* ln2b = (const float*)d_in[6];
  const float* w1   = (const float*)d_in[7];
  const float* b1   = (const float*)d_in[8];
  const float* w2   = (const float*)d_in[9];
  const float* b2   = (const float*)d_in[10];
  float* out = (float*)d_out;
  char* ws = (char*)d_ws;

  // ws layout (bytes); r/vT share one region (disjoint lifetimes), wqkvT aliases h.
  bf16_t* r     = (bf16_t*)(ws + 0);              // 16,777,216  [4096][2048]
  bf16_t* vT    = (bf16_t*)(ws + 0);              // same region [2][16][128][2048]
  bf16_t* qkv   = (bf16_t*)(ws + 16777216);       // 50,331,648  [4096][6144]
  bf16_t* w1T   = (bf16_t*)(ws + 67108864);       // 33,554,432  [8192][2048]
  bf16_t* w2T   = (bf16_t*)(ws + 100663296);      // 33,554,432  [2048][8192]
  bf16_t* h     = (bf16_t*)(ws + 134217728);      // 67,108,864  [4096][8192]
  bf16_t* wqkvT = (bf16_t*)(ws + 134217728);      // 25,165,824  [6144][2048] (dead before h is written)
  // total required: 201,326,592 bytes

  // weight transposes (f32 [K][N] -> bf16 [N][K])
  k_transpose_cvt<<<dim3(96, 32),  256, 0, stream>>>(wqkv, wqkvT, 2048, 6144);
  k_transpose_cvt<<<dim3(128, 32), 256, 0, stream>>>(w1,   w1T,   2048, 8192);
  k_transpose_cvt<<<dim3(32, 128), 256, 0, stream>>>(w2,   w2T,   8192, 2048);
  // LN1
  k_layernorm<<<4096, 256, 0, stream>>>(x, ln1s, ln1b, r);
  // QKV projection: M=4096, N=6144, K=2048 -> 16 x 48 = 768 blocks (3/CU)
  k_gemm2<0, 128><<<768, 512, 0, stream>>>(r, wqkvT, bqkv, qkv, nullptr, 6144, 2048);
  // V transpose for PV operand
  k_transpose_v<<<2048, 256, 0, stream>>>(qkv, vT);
  // attention + residual (writes every element of d_out)
  k_attn<<<512, 256, 0, stream>>>(qkv, vT, x, out);
  // LN2 on x2 = d_out
  k_layernorm<<<4096, 256, 0, stream>>>(out, ln2s, ln2b, r);
  // MLP1: M=4096, N=8192, K=2048 -> 16 x 32 = 512 blocks (2/CU)
  k_gemm2<1, 256><<<512, 512, 0, stream>>>(r, w1T, b1, h, nullptr, 8192, 2048);
  // MLP2: M=4096, N=2048, K=8192 -> 16 x 16 = 256 blocks (1/CU)
  k_gemm2<2, 128><<<256, 512, 0, stream>>>(h, w2T, b2, nullptr, out, 2048, 8192);
}